// Round 2
// 183.429 us; speedup vs baseline: 1.0622x; 1.0622x over previous
//
#include <hip/hip_runtime.h>

// LocallyConnectedLinear: out[b,h,w,o] = sum_k patch(x)[b,h,w,k] * W[h,w,k,o]
// k = c*9 + kh*3 + kw  (C slowest, per conv_general_dilated_patches NHWC)
// Shapes: x[8,32,32,64] f32, W[30,30,576,64] f32, out[8,30,30,64] f32.
//
// Memory-bound on the 132.7 MB weight stream (zero reuse across locations).
// One block per (h,w). Depth-2 register pipeline on the weight stream,
// weight prefetch issued BEFORE the x-staging barrier, nontemporal weight
// loads, shuffle-based epilogue (2 barriers, 6 KB partials).
//
// NOTE: weight quads use a native clang ext_vector type, not float4 —
// __builtin_nontemporal_load rejects HIP_vector_type classes.

#define HO 30
#define WO 30
#define HI 32
#define WI 32
#define CI 64
#define CO 64
#define BATCH 8
#define KTOT 576  // 64*3*3

typedef float f32x4 __attribute__((ext_vector_type(4)));

__global__ __launch_bounds__(256) void lc_kernel(const float* __restrict__ x,
                                                 const float* __restrict__ wgt,
                                                 float* __restrict__ out) {
    const int hw = blockIdx.x;          // 0..899
    const int h  = hw / WO;
    const int w  = hw - h * WO;
    const int tid  = threadIdx.x;
    const int lane = tid & 63;
    const int wv   = tid >> 6;          // wave 0..3
    const int o4   = tid & 15;          // channel quad: channels 4*o4..4*o4+3
    const int kg   = tid >> 4;          // k-group 0..15 (= wv*4 + kseg)
    const int kb   = kg * 36;           // this thread's k base

    __shared__ __align__(16) float xs[BATCH * KTOT];   // 18 KB x patches
    __shared__ f32x4 pbuf[3][BATCH][16];               // 6 KB cross-wave partials

    const f32x4* w4 = reinterpret_cast<const f32x4*>(
                          wgt + (size_t)hw * KTOT * CO) + o4;  // index: k*16

    // ---- Prefetch weight iterations 0 and 1 (overlaps x staging below) --
    f32x4 wb0[4], wb1[4];
    #pragma unroll
    for (int j = 0; j < 4; ++j)
        wb0[j] = __builtin_nontemporal_load(&w4[(kb + 0 + j) * 16]);
    #pragma unroll
    for (int j = 0; j < 4; ++j)
        wb1[j] = __builtin_nontemporal_load(&w4[(kb + 4 + j) * 16]);

    // ---- Stage x patches into LDS in k-order ----------------------------
    // idx enumerates (b, kh, kw, c) with c fastest -> coalesced global reads.
    // 8*9*64 = 4608 elements, exactly 18 iterations of 256 threads.
    #pragma unroll
    for (int it = 0; it < 18; ++it) {
        int idx = it * 256 + tid;
        int c  = idx & 63;
        int t  = idx >> 6;        // b*9 + kh*3 + kw
        int b  = t / 9;
        int r  = t - b * 9;
        int kh = r / 3;
        int kw = r - kh * 3;
        float v = x[((b * HI + h + kh) * WI + (w + kw)) * CI + c];
        // stride-9 LDS write: 9 coprime with 32 -> conflict-free
        xs[b * KTOT + c * 9 + kh * 3 + kw] = v;
    }
    __syncthreads();

    f32x4 acc[BATCH];
    #pragma unroll
    for (int b = 0; b < BATCH; ++b) acc[b] = (f32x4)0.f;

    // consume one 4-k slab from registers; x broadcast from LDS
    auto consume = [&](f32x4 (&cw)[4], int k0) {
        #pragma unroll
        for (int b = 0; b < BATCH; ++b) {
            f32x4 xv = *reinterpret_cast<const f32x4*>(&xs[b * KTOT + k0]);
            #pragma unroll
            for (int j = 0; j < 4; ++j) {
                acc[b][0] = fmaf(xv[j], cw[j][0], acc[b][0]);
                acc[b][1] = fmaf(xv[j], cw[j][1], acc[b][1]);
                acc[b][2] = fmaf(xv[j], cw[j][2], acc[b][2]);
                acc[b][3] = fmaf(xv[j], cw[j][3], acc[b][3]);
            }
        }
    };

    // ---- Main streaming loop: depth-2 software pipeline -----------------
    // even i -> wb0, odd i -> wb1; reload slot i for iteration i+2.
    #define RELOAD(buf, I)                                                   \
        {                                                                    \
            _Pragma("unroll")                                                \
            for (int j = 0; j < 4; ++j)                                      \
                buf[j] = __builtin_nontemporal_load(&w4[(kb + 4*(I) + j) * 16]); \
        }

    consume(wb0, kb + 0);  RELOAD(wb0, 2)
    consume(wb1, kb + 4);  RELOAD(wb1, 3)
    consume(wb0, kb + 8);  RELOAD(wb0, 4)
    consume(wb1, kb + 12); RELOAD(wb1, 5)
    consume(wb0, kb + 16); RELOAD(wb0, 6)
    consume(wb1, kb + 20); RELOAD(wb1, 7)
    consume(wb0, kb + 24); RELOAD(wb0, 8)
    consume(wb1, kb + 28);
    consume(wb0, kb + 32);
    #undef RELOAD

    // ---- Reduce: in-wave butterfly over kseg (lane bits 4,5) ------------
    #pragma unroll
    for (int b = 0; b < BATCH; ++b) {
        #pragma unroll
        for (int m = 16; m < 64; m <<= 1) {
            acc[b][0] += __shfl_xor(acc[b][0], m, 64);
            acc[b][1] += __shfl_xor(acc[b][1], m, 64);
            acc[b][2] += __shfl_xor(acc[b][2], m, 64);
            acc[b][3] += __shfl_xor(acc[b][3], m, 64);
        }
    }

    // cross-wave: waves 1..3 publish, wave 0 sums + stores
    if (wv > 0 && lane < 16) {
        #pragma unroll
        for (int b = 0; b < BATCH; ++b) pbuf[wv - 1][b][o4] = acc[b];
    }
    __syncthreads();
    if (wv == 0 && lane < 16) {
        #pragma unroll
        for (int b = 0; b < BATCH; ++b) {
            f32x4 s = acc[b];
            #pragma unroll
            for (int p = 0; p < 3; ++p) s += pbuf[p][b][o4];
            float* dst = out + (((size_t)b * HO + h) * WO + w) * CO + o4 * 4;
            *reinterpret_cast<f32x4*>(dst) = s;
        }
    }
}

extern "C" void kernel_launch(void* const* d_in, const int* in_sizes, int n_in,
                              void* d_out, int out_size, void* d_ws, size_t ws_size,
                              hipStream_t stream) {
    const float* x   = (const float*)d_in[0];
    const float* wgt = (const float*)d_in[1];
    float* out       = (float*)d_out;
    lc_kernel<<<dim3(HO * WO), dim3(256), 0, stream>>>(x, wgt, out);
}

// Round 3
// 182.124 us; speedup vs baseline: 1.0698x; 1.0072x over previous
//
#include <hip/hip_runtime.h>

// LocallyConnectedLinear: out[b,h,w,o] = sum_k patch(x)[b,h,w,k] * W[h,w,k,o]
// k = c*9 + kh*3 + kw  (C slowest, per conv_general_dilated_patches NHWC)
// Shapes: x[8,32,32,64] f32, W[30,30,576,64] f32, out[8,30,30,64] f32.
//
// Memory-bound on the 132.7 MB weight stream (zero reuse across locations).
// One block per (h,w). Depth-2 register pipeline on the weight stream,
// weight prefetch issued BEFORE the x-staging barrier, nontemporal weight
// loads, shuffle-based epilogue (2 barriers, 6 KB partials).
//
// This revision adds a bijective XCD-chunked block swizzle (900 % 8 != 0,
// so the m204 bijective form is required): blocks resident on the same XCD
// process a contiguous hw range, so the 9x-reused x patches hit that XCD's
// L2 instead of being re-fetched from HBM by all 8 XCDs (~13 MB saved).

#define HO 30
#define WO 30
#define HI 32
#define WI 32
#define CI 64
#define CO 64
#define BATCH 8
#define KTOT 576  // 64*3*3
#define NWG (HO * WO)   // 900
#define NXCD 8

typedef float f32x4 __attribute__((ext_vector_type(4)));

__global__ __launch_bounds__(256) void lc_kernel(const float* __restrict__ x,
                                                 const float* __restrict__ wgt,
                                                 float* __restrict__ out) {
    // ---- Bijective XCD-chunked swizzle ----------------------------------
    // Blocks with orig % 8 == c dispatch to XCD c (round-robin). Remap so
    // XCD c owns a contiguous chunk: sizes 113,113,113,113,112,112,112,112.
    const int orig = blockIdx.x;
    const int q = NWG / NXCD;          // 112
    const int r = NWG % NXCD;          // 4
    const int xcd = orig & 7;
    const int j   = orig >> 3;
    const int hw  = (xcd < r) ? xcd * (q + 1) + j
                              : r * (q + 1) + (xcd - r) * q + j;

    const int h  = hw / WO;
    const int w  = hw - h * WO;
    const int tid  = threadIdx.x;
    const int lane = tid & 63;
    const int wv   = tid >> 6;          // wave 0..3
    const int o4   = tid & 15;          // channel quad: channels 4*o4..4*o4+3
    const int kg   = tid >> 4;          // k-group 0..15 (= wv*4 + kseg)
    const int kb   = kg * 36;           // this thread's k base

    __shared__ __align__(16) float xs[BATCH * KTOT];   // 18 KB x patches
    __shared__ f32x4 pbuf[3][BATCH][16];               // 6 KB cross-wave partials

    const f32x4* w4 = reinterpret_cast<const f32x4*>(
                          wgt + (size_t)hw * KTOT * CO) + o4;  // index: k*16

    // ---- Prefetch weight iterations 0 and 1 (overlaps x staging below) --
    f32x4 wb0[4], wb1[4];
    #pragma unroll
    for (int jj = 0; jj < 4; ++jj)
        wb0[jj] = __builtin_nontemporal_load(&w4[(kb + 0 + jj) * 16]);
    #pragma unroll
    for (int jj = 0; jj < 4; ++jj)
        wb1[jj] = __builtin_nontemporal_load(&w4[(kb + 4 + jj) * 16]);

    // ---- Stage x patches into LDS in k-order ----------------------------
    // idx enumerates (b, kh, kw, c) with c fastest -> coalesced global reads.
    // 8*9*64 = 4608 elements, exactly 18 iterations of 256 threads.
    #pragma unroll
    for (int it = 0; it < 18; ++it) {
        int idx = it * 256 + tid;
        int c  = idx & 63;
        int t  = idx >> 6;        // b*9 + kh*3 + kw
        int b  = t / 9;
        int rr = t - b * 9;
        int kh = rr / 3;
        int kw = rr - kh * 3;
        float v = x[((b * HI + h + kh) * WI + (w + kw)) * CI + c];
        // stride-9 LDS write: 9 coprime with 32 -> conflict-free
        xs[b * KTOT + c * 9 + kh * 3 + kw] = v;
    }
    __syncthreads();

    f32x4 acc[BATCH];
    #pragma unroll
    for (int b = 0; b < BATCH; ++b) acc[b] = (f32x4)0.f;

    // consume one 4-k slab from registers; x broadcast from LDS
    auto consume = [&](f32x4 (&cw)[4], int k0) {
        #pragma unroll
        for (int b = 0; b < BATCH; ++b) {
            f32x4 xv = *reinterpret_cast<const f32x4*>(&xs[b * KTOT + k0]);
            #pragma unroll
            for (int jj = 0; jj < 4; ++jj) {
                acc[b][0] = fmaf(xv[jj], cw[jj][0], acc[b][0]);
                acc[b][1] = fmaf(xv[jj], cw[jj][1], acc[b][1]);
                acc[b][2] = fmaf(xv[jj], cw[jj][2], acc[b][2]);
                acc[b][3] = fmaf(xv[jj], cw[jj][3], acc[b][3]);
            }
        }
    };

    // ---- Main streaming loop: depth-2 software pipeline -----------------
    // even i -> wb0, odd i -> wb1; reload slot i for iteration i+2.
    #define RELOAD(buf, I)                                                   \
        {                                                                    \
            _Pragma("unroll")                                                \
            for (int jj = 0; jj < 4; ++jj)                                   \
                buf[jj] = __builtin_nontemporal_load(&w4[(kb + 4*(I) + jj) * 16]); \
        }

    consume(wb0, kb + 0);  RELOAD(wb0, 2)
    consume(wb1, kb + 4);  RELOAD(wb1, 3)
    consume(wb0, kb + 8);  RELOAD(wb0, 4)
    consume(wb1, kb + 12); RELOAD(wb1, 5)
    consume(wb0, kb + 16); RELOAD(wb0, 6)
    consume(wb1, kb + 20); RELOAD(wb1, 7)
    consume(wb0, kb + 24); RELOAD(wb0, 8)
    consume(wb1, kb + 28);
    consume(wb0, kb + 32);
    #undef RELOAD

    // ---- Reduce: in-wave butterfly over kseg (lane bits 4,5) ------------
    #pragma unroll
    for (int b = 0; b < BATCH; ++b) {
        #pragma unroll
        for (int m = 16; m < 64; m <<= 1) {
            acc[b][0] += __shfl_xor(acc[b][0], m, 64);
            acc[b][1] += __shfl_xor(acc[b][1], m, 64);
            acc[b][2] += __shfl_xor(acc[b][2], m, 64);
            acc[b][3] += __shfl_xor(acc[b][3], m, 64);
        }
    }

    // cross-wave: waves 1..3 publish, wave 0 sums + stores
    if (wv > 0 && lane < 16) {
        #pragma unroll
        for (int b = 0; b < BATCH; ++b) pbuf[wv - 1][b][o4] = acc[b];
    }
    __syncthreads();
    if (wv == 0 && lane < 16) {
        #pragma unroll
        for (int b = 0; b < BATCH; ++b) {
            f32x4 s = acc[b];
            #pragma unroll
            for (int p = 0; p < 3; ++p) s += pbuf[p][b][o4];
            float* dst = out + (((size_t)b * HO + h) * WO + w) * CO + o4 * 4;
            *reinterpret_cast<f32x4*>(dst) = s;
        }
    }
}

extern "C" void kernel_launch(void* const* d_in, const int* in_sizes, int n_in,
                              void* d_out, int out_size, void* d_ws, size_t ws_size,
                              hipStream_t stream) {
    const float* x   = (const float*)d_in[0];
    const float* wgt = (const float*)d_in[1];
    float* out       = (float*)d_out;
    lc_kernel<<<dim3(NWG), dim3(256), 0, stream>>>(x, wgt, out);
}

// Round 4
// 181.145 us; speedup vs baseline: 1.0756x; 1.0054x over previous
//
#include <hip/hip_runtime.h>

// LocallyConnectedLinear: out[b,h,w,o] = sum_k patch(x)[b,h,w,k] * W[h,w,k,o]
// k = c*9 + kh*3 + kw  (C slowest, per conv_general_dilated_patches NHWC)
// Shapes: x[8,32,32,64] f32, W[30,30,576,64] f32, out[8,30,30,64] f32.
//
// Memory-bound on the 132.7 MB weight stream (zero reuse across locations).
// One block per (h,w), bijective XCD-chunked swizzle for x L2 locality.
// This revision: depth-3 register pipeline on the weight stream (12
// dwordx4 in flight per wave) and a fully parallel epilogue (all 4 waves
// publish partials, each wave reduces+stores 2 batches) replacing the
// wave-0-serial reduction.

#define HO 30
#define WO 30
#define HI 32
#define WI 32
#define CI 64
#define CO 64
#define BATCH 8
#define KTOT 576  // 64*3*3
#define NWG (HO * WO)   // 900
#define NXCD 8

typedef float f32x4 __attribute__((ext_vector_type(4)));

__global__ __launch_bounds__(256) void lc_kernel(const float* __restrict__ x,
                                                 const float* __restrict__ wgt,
                                                 float* __restrict__ out) {
    // ---- Bijective XCD-chunked swizzle (900 % 8 != 0 -> m204 form) ------
    const int orig = blockIdx.x;
    const int q = NWG / NXCD;          // 112
    const int r = NWG % NXCD;          // 4
    const int xcd = orig & 7;
    const int j   = orig >> 3;
    const int hw  = (xcd < r) ? xcd * (q + 1) + j
                              : r * (q + 1) + (xcd - r) * q + j;

    const int h  = hw / WO;
    const int w  = hw - h * WO;
    const int tid  = threadIdx.x;
    const int lane = tid & 63;
    const int wv   = tid >> 6;          // wave 0..3
    const int o4   = tid & 15;          // channel quad: channels 4*o4..4*o4+3
    const int kg   = tid >> 4;          // k-group 0..15 (= wv*4 + kseg)
    const int kb   = kg * 36;           // this thread's k base

    __shared__ __align__(16) float xs[BATCH * KTOT];   // 18 KB x patches
    __shared__ f32x4 pbuf[4][BATCH][16];               // 8 KB cross-wave partials

    const f32x4* w4 = reinterpret_cast<const f32x4*>(
                          wgt + (size_t)hw * KTOT * CO) + o4;  // index: k*16

    // ---- Prefetch weight slabs 0,1,2 (overlaps x staging below) ---------
    f32x4 wb0[4], wb1[4], wb2[4];
    #pragma unroll
    for (int jj = 0; jj < 4; ++jj)
        wb0[jj] = __builtin_nontemporal_load(&w4[(kb + 0 + jj) * 16]);
    #pragma unroll
    for (int jj = 0; jj < 4; ++jj)
        wb1[jj] = __builtin_nontemporal_load(&w4[(kb + 4 + jj) * 16]);
    #pragma unroll
    for (int jj = 0; jj < 4; ++jj)
        wb2[jj] = __builtin_nontemporal_load(&w4[(kb + 8 + jj) * 16]);

    // ---- Stage x patches into LDS in k-order ----------------------------
    // idx enumerates (b, kh, kw, c) with c fastest -> coalesced global reads.
    // 8*9*64 = 4608 elements, exactly 18 iterations of 256 threads.
    #pragma unroll
    for (int it = 0; it < 18; ++it) {
        int idx = it * 256 + tid;
        int c  = idx & 63;
        int t  = idx >> 6;        // b*9 + kh*3 + kw
        int b  = t / 9;
        int rr = t - b * 9;
        int kh = rr / 3;
        int kw = rr - kh * 3;
        float v = x[((b * HI + h + kh) * WI + (w + kw)) * CI + c];
        // stride-9 LDS write: 9 coprime with 32 -> conflict-free
        xs[b * KTOT + c * 9 + kh * 3 + kw] = v;
    }
    __syncthreads();

    f32x4 acc[BATCH];
    #pragma unroll
    for (int b = 0; b < BATCH; ++b) acc[b] = (f32x4)0.f;

    // consume one 4-k slab from registers; x broadcast from LDS
    // (4 distinct b128 addrs per wave, banks 0-3/4-7/8-11/12-15: conflict-free)
    auto consume = [&](f32x4 (&cw)[4], int k0) {
        #pragma unroll
        for (int b = 0; b < BATCH; ++b) {
            f32x4 xv = *reinterpret_cast<const f32x4*>(&xs[b * KTOT + k0]);
            #pragma unroll
            for (int jj = 0; jj < 4; ++jj) {
                acc[b][0] = fmaf(xv[jj], cw[jj][0], acc[b][0]);
                acc[b][1] = fmaf(xv[jj], cw[jj][1], acc[b][1]);
                acc[b][2] = fmaf(xv[jj], cw[jj][2], acc[b][2]);
                acc[b][3] = fmaf(xv[jj], cw[jj][3], acc[b][3]);
            }
        }
    };

    // ---- Main streaming loop: depth-3 software pipeline -----------------
    // slab i lives in buf[i % 3]; reload slot i for slab i+3.
    #define RELOAD(buf, I)                                                   \
        {                                                                    \
            _Pragma("unroll")                                                \
            for (int jj = 0; jj < 4; ++jj)                                   \
                buf[jj] = __builtin_nontemporal_load(&w4[(kb + 4*(I) + jj) * 16]); \
        }

    consume(wb0, kb + 0);  RELOAD(wb0, 3)
    consume(wb1, kb + 4);  RELOAD(wb1, 4)
    consume(wb2, kb + 8);  RELOAD(wb2, 5)
    consume(wb0, kb + 12); RELOAD(wb0, 6)
    consume(wb1, kb + 16); RELOAD(wb1, 7)
    consume(wb2, kb + 20); RELOAD(wb2, 8)
    consume(wb0, kb + 24);
    consume(wb1, kb + 28);
    consume(wb2, kb + 32);
    #undef RELOAD

    // ---- Reduce: in-wave butterfly over kseg (lane bits 4,5) ------------
    #pragma unroll
    for (int b = 0; b < BATCH; ++b) {
        #pragma unroll
        for (int m = 16; m < 64; m <<= 1) {
            acc[b][0] += __shfl_xor(acc[b][0], m, 64);
            acc[b][1] += __shfl_xor(acc[b][1], m, 64);
            acc[b][2] += __shfl_xor(acc[b][2], m, 64);
            acc[b][3] += __shfl_xor(acc[b][3], m, 64);
        }
    }

    // ---- Parallel cross-wave reduce: every wave publishes, every wave
    // reduces + stores 2 batches (b = 2*wv, 2*wv+1) with 32 lanes ---------
    if (lane < 16) {
        #pragma unroll
        for (int b = 0; b < BATCH; ++b) pbuf[wv][b][o4] = acc[b];
    }
    __syncthreads();
    if (lane < 32) {
        const int b   = 2 * wv + (lane >> 4);
        const int oo4 = lane & 15;
        // 32 consecutive float4 per wave -> contiguous, conflict-free
        f32x4 s = pbuf[0][b][oo4] + pbuf[1][b][oo4]
                + pbuf[2][b][oo4] + pbuf[3][b][oo4];
        float* dst = out + (((size_t)b * HO + h) * WO + w) * CO + oo4 * 4;
        *reinterpret_cast<f32x4*>(dst) = s;
    }
}

extern "C" void kernel_launch(void* const* d_in, const int* in_sizes, int n_in,
                              void* d_out, int out_size, void* d_ws, size_t ws_size,
                              hipStream_t stream) {
    const float* x   = (const float*)d_in[0];
    const float* wgt = (const float*)d_in[1];
    float* out       = (float*)d_out;
    lc_kernel<<<dim3(NWG), dim3(256), 0, stream>>>(x, wgt, out);
}